// Round 1
// baseline (358.706 us; speedup 1.0000x reference)
//
#include <hip/hip_runtime.h>

// Problem constants
#define NB 4096   // batches
#define NT 64     // tokens
#define ND 128    // d_model
#define NTD 8192  // NT*ND

using bf16x8 = __attribute__((ext_vector_type(8))) short;
using s16x4  = __attribute__((ext_vector_type(4))) short;
using f32x4  = __attribute__((ext_vector_type(4))) float;

__device__ __forceinline__ short f2bf(float x) {
  union { float f; unsigned u; } v; v.f = x;
  unsigned r = (v.u + 0x7FFFu + ((v.u >> 16) & 1u)) >> 16;
  return (short)r;
}
__device__ __forceinline__ float bf2f(short h) {
  union { unsigned u; float f; } v; v.u = ((unsigned)(unsigned short)h) << 16;
  return v.f;
}

// ---------------------------------------------------------------------------
// Kernel: convert W1, W2 to bf16
// ---------------------------------------------------------------------------
__global__ __launch_bounds__(256) void k_cvt(const float* __restrict__ W1,
                                             const float* __restrict__ W2,
                                             short* __restrict__ W1b,
                                             short* __restrict__ W2b) {
  int idx = blockIdx.x * 256 + threadIdx.x;  // 0..524287 float4s (2 x 1M floats)
  const float4* src; short* dst;
  if (idx < 262144) { src = (const float4*)W1; dst = W1b; }
  else { idx -= 262144; src = (const float4*)W2; dst = W2b; }
  float4 v = src[idx];
  s16x4 p = { f2bf(v.x), f2bf(v.y), f2bf(v.z), f2bf(v.w) };
  *(s16x4*)&dst[4 * idx] = p;
}

// ---------------------------------------------------------------------------
// Kernel: per-batch attention.  ydot = softmax(X X^T / sqrt(D)) X + X  (bf16)
// One block (4 waves) per batch.
// ---------------------------------------------------------------------------
#define LDX 136  // padded row stride (shorts) for 128-wide rows; 272B = 17*16
#define LDT 72   // padded row stride for 64-wide rows; 144B = 9*16
#define LDP 72

__global__ __launch_bounds__(256) void k_attn(const float* __restrict__ X,
                                              short* __restrict__ ydot) {
  __shared__ short Xl[NT * LDX];    // X[b] row-major (token x d), bf16
  __shared__ short XT[ND * LDT];    // X[b] transposed (d x token)
  __shared__ short Pl[4][16 * LDP]; // per-wave softmax tiles (16 rows x 64)

  const int b = blockIdx.x;
  const int tid = threadIdx.x;
  const float4* X4 = (const float4*)(X + (size_t)b * NTD);

  // Stage X[b] (64x128 fp32) -> LDS bf16 (row-major + transposed)
  for (int it = 0; it < 8; ++it) {
    int idx = tid + 256 * it;        // 0..2047 float4s
    int r = idx >> 5;                // 32 float4 per row
    int c4 = idx & 31;
    float4 v = X4[idx];
    short h0 = f2bf(v.x), h1 = f2bf(v.y), h2 = f2bf(v.z), h3 = f2bf(v.w);
    s16x4 p = { h0, h1, h2, h3 };
    *(s16x4*)&Xl[r * LDX + 4 * c4] = p;
    int c = 4 * c4;
    XT[(c + 0) * LDT + r] = h0;
    XT[(c + 1) * LDT + r] = h1;
    XT[(c + 2) * LDT + r] = h2;
    XT[(c + 3) * LDT + r] = h3;
  }
  __syncthreads();

  const int w = tid >> 6;
  const int l = tid & 63;
  const int g = l >> 4;
  const int ln = l & 15;

  // S = X X^T / sqrt(D) : wave w computes rows [16w,16w+16), 4 col-tiles
  f32x4 S[4];
  for (int tj = 0; tj < 4; ++tj) S[tj] = f32x4{0.f, 0.f, 0.f, 0.f};
  for (int kk = 0; kk < 4; ++kk) {
    bf16x8 a = *(const bf16x8*)&Xl[(16 * w + ln) * LDX + 32 * kk + 8 * g];
    for (int tj = 0; tj < 4; ++tj) {
      bf16x8 bb = *(const bf16x8*)&Xl[(16 * tj + ln) * LDX + 32 * kk + 8 * g];
      S[tj] = __builtin_amdgcn_mfma_f32_16x16x32_bf16(a, bb, S[tj], 0, 0, 0);
    }
  }

  // Wave-parallel softmax.  C layout: row = 4g+i (local), col = 16*tj + ln.
  const float scale = 0.08838834764831845f;  // 1/sqrt(128)
  float li[4];
  for (int i = 0; i < 4; ++i) {
    float p[4];
    float mx = -1e30f;
    for (int tj = 0; tj < 4; ++tj) {
      float s = S[tj][i] * scale;
      p[tj] = s;
      mx = fmaxf(mx, s);
    }
    for (int msk = 1; msk < 16; msk <<= 1) mx = fmaxf(mx, __shfl_xor(mx, msk));
    float sum = 0.f;
    for (int tj = 0; tj < 4; ++tj) {
      float e = __expf(p[tj] - mx);
      p[tj] = e;
      sum += e;
    }
    for (int msk = 1; msk < 16; msk <<= 1) sum += __shfl_xor(sum, msk);
    li[i] = 1.0f / sum;
    for (int tj = 0; tj < 4; ++tj)
      Pl[w][(4 * g + i) * LDP + 16 * tj + ln] = f2bf(p[tj]);
  }
  __syncthreads();  // conservative: order Pl writes before reads

  // PV: X_dot rows [16w,16w+16) = P (16x64) @ X (64x128); then + X, store bf16
  bf16x8 a0 = *(const bf16x8*)&Pl[w][ln * LDP + 8 * g];
  bf16x8 a1 = *(const bf16x8*)&Pl[w][ln * LDP + 32 + 8 * g];
  short* yrow = ydot + (size_t)b * NTD;
  for (int c = 0; c < 8; ++c) {
    f32x4 acc = f32x4{0.f, 0.f, 0.f, 0.f};
    bf16x8 b0 = *(const bf16x8*)&XT[(16 * c + ln) * LDT + 8 * g];
    bf16x8 b1 = *(const bf16x8*)&XT[(16 * c + ln) * LDT + 32 + 8 * g];
    acc = __builtin_amdgcn_mfma_f32_16x16x32_bf16(a0, b0, acc, 0, 0, 0);
    acc = __builtin_amdgcn_mfma_f32_16x16x32_bf16(a1, b1, acc, 0, 0, 0);
    for (int i = 0; i < 4; ++i) {
      int row = 16 * w + 4 * g + i;  // token
      int col = 16 * c + ln;         // d
      float y = acc[i] * li[i] + bf2f(Xl[row * LDX + col]);
      yrow[row * ND + col] = f2bf(y);
    }
  }
}

// ---------------------------------------------------------------------------
// Kernel: GEMM1 partial: hacc += X(bf16-cast) @ W1^T.  Split-K with atomics.
// grid (64 Mtiles, 16 Ksplits), BM=64, BN=128, K-chunk 512 (16 steps of 32)
// ---------------------------------------------------------------------------
#define LDA1 40  // 32 + 8 pad; 80B rows (16B aligned)

__global__ __launch_bounds__(256) void k_gemm1(const float* __restrict__ X,
                                               const short* __restrict__ W1b,
                                               float* __restrict__ hacc) {
  __shared__ short Al[64 * LDA1];
  __shared__ short Bl[128 * LDA1];
  const int mt = blockIdx.x;
  const int kz = blockIdx.y;
  const int tid = threadIdx.x;
  const int w = tid >> 6, l = tid & 63, g = l >> 4, ln = l & 15;

  f32x4 acc[8];
  for (int c = 0; c < 8; ++c) acc[c] = f32x4{0.f, 0.f, 0.f, 0.f};

  for (int s = 0; s < 16; ++s) {
    int kb = kz * 512 + s * 32;
    // stage A: 64 rows x 32 k from fp32 X (convert to bf16)
    for (int it = 0; it < 2; ++it) {
      int idx = tid + 256 * it;      // 0..511
      int r = idx >> 3, f = idx & 7;
      float4 v = ((const float4*)X)[(size_t)(mt * 64 + r) * 2048 + (kb >> 2) + f];
      s16x4 p = { f2bf(v.x), f2bf(v.y), f2bf(v.z), f2bf(v.w) };
      *(s16x4*)&Al[r * LDA1 + 4 * f] = p;
    }
    // stage B: 128 rows x 32 k from W1b
    for (int it = 0; it < 2; ++it) {
      int idx = tid + 256 * it;      // 0..511
      int n = idx >> 2, f = idx & 3;
      bf16x8 v = *(const bf16x8*)&W1b[(size_t)n * NTD + kb + 8 * f];
      *(bf16x8*)&Bl[n * LDA1 + 8 * f] = v;
    }
    __syncthreads();
    bf16x8 a = *(const bf16x8*)&Al[(16 * w + ln) * LDA1 + 8 * g];
    for (int c = 0; c < 8; ++c) {
      bf16x8 bb = *(const bf16x8*)&Bl[(16 * c + ln) * LDA1 + 8 * g];
      acc[c] = __builtin_amdgcn_mfma_f32_16x16x32_bf16(a, bb, acc[c], 0, 0, 0);
    }
    __syncthreads();
  }
  for (int c = 0; c < 8; ++c)
    for (int i = 0; i < 4; ++i) {
      int m = mt * 64 + 16 * w + 4 * g + i;
      int n = 16 * c + ln;
      atomicAdd(&hacc[m * ND + n], acc[c][i]);
    }
}

// ---------------------------------------------------------------------------
// Kernel: h = bf16(relu(hacc + b1))
// ---------------------------------------------------------------------------
__global__ __launch_bounds__(256) void k_hact(const float* __restrict__ hacc,
                                              const float* __restrict__ b1,
                                              short* __restrict__ hb) {
  int idx = blockIdx.x * 256 + threadIdx.x;  // 0..524287
  float v = hacc[idx] + b1[idx & 127];
  hb[idx] = f2bf(fmaxf(v, 0.f));
}

// ---------------------------------------------------------------------------
// Kernel: GEMM2 + residual + LayerNorm.
// out = LN(h @ W2^T + b2 + ydot) * gamma + beta
// grid (64 Mtiles, 64 Ntiles), BM=64, BN=128, K=128 (4 MFMA steps)
// BN=128 == one full LN row per output-tile row.
// ---------------------------------------------------------------------------
#define LDK 136

__global__ __launch_bounds__(256) void k_gemm2(const short* __restrict__ hb,
                                               const short* __restrict__ W2b,
                                               const short* __restrict__ ydot,
                                               const float* __restrict__ b2,
                                               const float* __restrict__ gamma,
                                               const float* __restrict__ beta,
                                               float* __restrict__ out) {
  __shared__ short Al[64 * LDK];
  __shared__ short Bl[128 * LDK];
  __shared__ short Yl[64 * LDK];
  __shared__ float g_s[128], be_s[128], b2_s[128];

  const int mt = blockIdx.x, nt = blockIdx.y;
  const int tid = threadIdx.x;

  for (int it = 0; it < 4; ++it) {     // A: h tile 64x128
    int idx = tid + 256 * it;          // 0..1023
    int r = idx >> 4, f = idx & 15;
    *(bf16x8*)&Al[r * LDK + 8 * f] =
        *(const bf16x8*)&hb[(size_t)(mt * 64 + r) * ND + 8 * f];
  }
  for (int it = 0; it < 8; ++it) {     // B: W2 tile 128x128
    int idx = tid + 256 * it;          // 0..2047
    int n = idx >> 4, f = idx & 15;
    *(bf16x8*)&Bl[n * LDK + 8 * f] =
        *(const bf16x8*)&W2b[(size_t)(nt * 128 + n) * ND + 8 * f];
  }
  for (int it = 0; it < 4; ++it) {     // ydot tile 64x128
    int idx = tid + 256 * it;
    int r = idx >> 4, f = idx & 15;
    *(bf16x8*)&Yl[r * LDK + 8 * f] =
        *(const bf16x8*)&ydot[(size_t)(mt * 64 + r) * NTD + nt * 128 + 8 * f];
  }
  if (tid < 128) {
    g_s[tid] = gamma[tid];
    be_s[tid] = beta[tid];
    b2_s[tid] = b2[nt * 128 + tid];
  }
  __syncthreads();

  const int w = tid >> 6, l = tid & 63, g = l >> 4, ln = l & 15;
  f32x4 acc[8];
  for (int c = 0; c < 8; ++c) acc[c] = f32x4{0.f, 0.f, 0.f, 0.f};
  for (int kk = 0; kk < 4; ++kk) {
    bf16x8 a = *(const bf16x8*)&Al[(16 * w + ln) * LDK + 32 * kk + 8 * g];
    for (int c = 0; c < 8; ++c) {
      bf16x8 bb = *(const bf16x8*)&Bl[(16 * c + ln) * LDK + 32 * kk + 8 * g];
      acc[c] = __builtin_amdgcn_mfma_f32_16x16x32_bf16(a, bb, acc[c], 0, 0, 0);
    }
  }

  // Epilogue: +b2 +ydot, LayerNorm across the 128 cols of each row.
  for (int i = 0; i < 4; ++i) {
    int lr = 16 * w + 4 * g + i;   // local row (batch within tile)
    float v[8];
    float s = 0.f;
    for (int c = 0; c < 8; ++c) {
      int d = 16 * c + ln;
      v[c] = acc[c][i] + b2_s[d] + bf2f(Yl[lr * LDK + d]);
      s += v[c];
    }
    for (int msk = 1; msk < 16; msk <<= 1) s += __shfl_xor(s, msk);
    float mu = s * (1.f / 128.f);
    float s2 = 0.f;
    for (int c = 0; c < 8; ++c) { float d2 = v[c] - mu; s2 += d2 * d2; }
    for (int msk = 1; msk < 16; msk <<= 1) s2 += __shfl_xor(s2, msk);
    float rstd = rsqrtf(s2 * (1.f / 128.f) + 1e-5f);
    size_t base = (size_t)(mt * 64 + lr) * NTD + (size_t)nt * 128;
    for (int c = 0; c < 8; ++c) {
      int d = 16 * c + ln;
      out[base + d] = (v[c] - mu) * rstd * g_s[d] + be_s[d];
    }
  }
}

// ---------------------------------------------------------------------------
extern "C" void kernel_launch(void* const* d_in, const int* in_sizes, int n_in,
                              void* d_out, int out_size, void* d_ws, size_t ws_size,
                              hipStream_t stream) {
  const float* X     = (const float*)d_in[0];
  const float* W1    = (const float*)d_in[1];
  const float* b1    = (const float*)d_in[2];
  const float* W2    = (const float*)d_in[3];
  const float* b2    = (const float*)d_in[4];
  const float* gamma = (const float*)d_in[5];
  const float* beta  = (const float*)d_in[6];
  float* out = (float*)d_out;

  char* ws = (char*)d_ws;
  short* ydot = (short*)ws;                               // 64 MB
  short* W1b  = (short*)(ws + 67108864);                  // 2 MB
  short* W2b  = (short*)(ws + 67108864 + 2097152);        // 2 MB
  float* hacc = (float*)(ws + 67108864 + 2 * 2097152);    // 2 MB
  short* hb   = (short*)(ws + 67108864 + 3 * 2097152);    // 1 MB

  hipMemsetAsync(hacc, 0, (size_t)NB * ND * sizeof(float), stream);
  k_cvt<<<2048, 256, 0, stream>>>(W1, W2, W1b, W2b);
  k_attn<<<NB, 256, 0, stream>>>(X, ydot);
  k_gemm1<<<dim3(64, 16), 256, 0, stream>>>(X, W1b, hacc);
  k_hact<<<2048, 256, 0, stream>>>(hacc, b1, hb);
  k_gemm2<<<dim3(64, 64), 256, 0, stream>>>(hb, W2b, ydot, b2, gamma, beta, out);
}